// Round 13
// baseline (232.899 us; speedup 1.0000x reference)
//
#include <hip/hip_runtime.h>
#include <math.h>

// EfficientDet post-processing v13 (4 launches).
// prep(transpose vec4, 128-anchor tiles) -> select(sorted top-512 per
// (class,slice) + decode) -> snms(resume-bitonic + direct-write mask with
// stride-17 rows (bank-conflict-free) + 2-wide greedy scan + compact)
// -> final(hist-select top-100).

#define A_N   110484
#define C_N   90
#define KCAND 512
#define NBINS 8192        // 13-bit histogram bins (key >> 19)
#define KSH   19
#define MAXDET 100
#define IMG_F 768.0f
#define THRESH 0.05f
#define NS    4                                   // slices per class
#define VTOT  (A_N / 4)                           // 27621 vec4 units
#define VS4   ((VTOT + NS - 1) / NS)              // 6906
#define SL_CAP 1024                               // per-slice candidate cap
#define CAND_N (NS * KCAND)                       // 2048 per class (sorted runs)
#define KEEP_CAP 100
#define TILE_A 128
#define T_BLKS ((A_N + TILE_A - 1) / TILE_A)      // 864 transpose blocks
#define S_BLKS (C_N * NS)                         // 360 select blocks
#define D_BLKS ((A_N + 255) / 256)                // 432 decode blocks
#define FCAP  512                                 // final collect capacity
#define MSTR  17                                  // bmask row stride (odd = conflict-free)

typedef unsigned int u32;
typedef unsigned long long u64;

__device__ __forceinline__ u32 fkey(float f) {
    u32 u = __float_as_uint(f);
    return (u & 0x80000000u) ? ~u : (u | 0x80000000u);
}
__device__ __forceinline__ float unfkey(u32 k) {
    u32 u = (k & 0x80000000u) ? (k ^ 0x80000000u) : ~k;
    return __uint_as_float(u);
}
__device__ __forceinline__ u64 shflx64(u64 v, int m) {
    u32 lo = (u32)__shfl_xor((int)(u32)v, m, 64);
    u32 hi = (u32)__shfl_xor((int)(v >> 32), m, 64);
    return ((u64)hi << 32) | lo;
}

// ------- Stage 1: transpose (sigmoid->key, vec4 loads, 128-anchor tiles) -------
__global__ __launch_bounds__(256)
void prep_kernel(const float* __restrict__ cls,
                 u32* __restrict__ keysT) {
    __shared__ u32 tile[TILE_A * 91];   // 46.6 KB, stride 91 (odd) = conflict-free
    const int a0 = blockIdx.x * TILE_A;
    const int lim = min(TILE_A, A_N - a0);       // 128 or 20; lim*90 % 4 == 0
    const int n4 = (lim * C_N) >> 2;
    const float4* src4 = (const float4*)(cls + (size_t)a0 * C_N);
    for (int i4 = threadIdx.x; i4 < n4; i4 += 256) {
        float4 x4 = src4[i4];
        const u32 base = (u32)(4 * i4);
        float xs[4] = { x4.x, x4.y, x4.z, x4.w };
        #pragma unroll
        for (int k = 0; k < 4; ++k) {
            u32 i = base + k;
            u32 aa = i / C_N, c = i % C_N;
            float s = 1.0f / (1.0f + expf(-xs[k]));
            tile[aa * 91 + c] = fkey(s);
        }
    }
    __syncthreads();
    for (int j = threadIdx.x; j < C_N * TILE_A; j += 256) {
        int c = j >> 7, aa = j & (TILE_A - 1);
        if (aa < lim)
            keysT[(size_t)c * A_N + a0 + aa] = tile[aa * 91 + c];
    }
}

// ---- Stage 2: per-(class,slice) exact sorted top-512 (+ decode blocks) ----
__global__ __launch_bounds__(256)
void select_kernel(const u32* __restrict__ keysT,
                   const float* __restrict__ anchors,
                   const float* __restrict__ reg,
                   float4* __restrict__ boxes,
                   u64* __restrict__ candbuf) {
    __shared__ u32 hist[NBINS];    // 32 KB
    __shared__ u32 csum[256];
    __shared__ u64 lbuf[SL_CAP];   // 8 KB
    __shared__ u32 sPv;
    __shared__ int lcnt;
    const int tid = threadIdx.x;

    if (blockIdx.x >= S_BLKS) {    // decode blocks
        int a = (blockIdx.x - S_BLKS) * 256 + tid;
        if (a < A_N) {
            float4 an = ((const float4*)anchors)[a];
            float4 dl = ((const float4*)reg)[a];
            float wa = an.z - an.x, ha = an.w - an.y;
            float cx = an.x + 0.5f * wa + dl.x * wa;
            float cy = an.y + 0.5f * ha + dl.y * ha;
            float w = expf(dl.z) * wa;
            float h = expf(dl.w) * ha;
            float4 o;
            o.x = fminf(fmaxf(cx - 0.5f * w, 0.0f), IMG_F);
            o.y = fminf(fmaxf(cy - 0.5f * h, 0.0f), IMG_F);
            o.z = fminf(fmaxf(cx + 0.5f * w, 0.0f), IMG_F);
            o.w = fminf(fmaxf(cy + 0.5f * h, 0.0f), IMG_F);
            boxes[a] = o;
        }
        return;
    }
    const int c = blockIdx.x >> 2, s = blockIdx.x & 3;
    const int lo = s * VS4, hiEnd = min(VTOT, lo + VS4);
    const uint4* kv = (const uint4*)(keysT + (size_t)c * A_N);

    for (int i = tid; i < NBINS; i += 256) hist[i] = 0;
    if (tid == 0) { sPv = 0; lcnt = 0; }
    __syncthreads();
    for (int i = lo + tid; i < hiEnd; i += 256) {
        uint4 k = kv[i];
        atomicAdd(&hist[k.x >> KSH], 1u);
        atomicAdd(&hist[k.y >> KSH], 1u);
        atomicAdd(&hist[k.z >> KSH], 1u);
        atomicAdd(&hist[k.w >> KSH], 1u);
    }
    __syncthreads();
    u32 own = 0; const int hi = NBINS - 1 - 32 * tid;
    #pragma unroll 4
    for (int j = 0; j < 32; ++j) own += hist[hi - j];
    csum[tid] = own;
    __syncthreads();
    for (int off = 1; off < 256; off <<= 1) {
        u32 v = csum[tid];
        u32 a = (tid >= off) ? csum[tid - off] : 0u;
        __syncthreads();
        csum[tid] = v + a;
        __syncthreads();
    }
    const u32 incl = csum[tid], excl = incl - own;
    if (excl < (u32)KCAND && incl >= (u32)KCAND) {
        u32 cum = excl;
        for (int j = 0; j < 32; ++j) {
            u32 hv = hist[hi - j];
            if (cum + hv >= (u32)KCAND) { sPv = (u32)(hi - j); break; }
            cum += hv;
        }
    }
    __syncthreads();
    const u32 P = sPv;
    for (int i = lo + tid; i < hiEnd; i += 256) {
        uint4 k = kv[i];
        u32 base = (u32)(4 * i);
        if ((k.x >> KSH) >= P) {
            int p = atomicAdd(&lcnt, 1);
            if (p < SL_CAP) lbuf[p] = (((u64)(~k.x)) << 32) | base;
        }
        if ((k.y >> KSH) >= P) {
            int p = atomicAdd(&lcnt, 1);
            if (p < SL_CAP) lbuf[p] = (((u64)(~k.y)) << 32) | (base + 1);
        }
        if ((k.z >> KSH) >= P) {
            int p = atomicAdd(&lcnt, 1);
            if (p < SL_CAP) lbuf[p] = (((u64)(~k.z)) << 32) | (base + 2);
        }
        if ((k.w >> KSH) >= P) {
            int p = atomicAdd(&lcnt, 1);
            if (p < SL_CAP) lbuf[p] = (((u64)(~k.w)) << 32) | (base + 3);
        }
    }
    __syncthreads();
    const int n = min(lcnt, SL_CAP);   // n >= 512 guaranteed by pivot
    for (int i = tid; i < SL_CAP; i += 256) if (i >= n) lbuf[i] = ~0ULL;
    __syncthreads();

    // --- hybrid bitonic 1024 sort: 4 waves x (4 regs x 64 lanes) ---
    {
        const int l = tid & 63, w = tid >> 6;
        int ii[4]; u64 v[4];
        #pragma unroll
        for (int r = 0; r < 4; ++r) { ii[r] = 256 * w + 64 * r + l; v[r] = lbuf[ii[r]]; }
        __syncthreads();
        #pragma unroll
        for (u32 kk = 2; kk <= 1024; kk <<= 1) {
            #pragma unroll
            for (u32 j = kk >> 1; j > 0; j >>= 1) {
                if (j >= 256) {
                    #pragma unroll
                    for (int r = 0; r < 4; ++r) lbuf[ii[r]] = v[r];
                    __syncthreads();
                    #pragma unroll
                    for (int r = 0; r < 4; ++r) {
                        u64 pv = lbuf[ii[r] ^ j];
                        bool up = ((ii[r] & kk) == 0);
                        bool m = (((ii[r] & j) == 0) == up);
                        v[r] = m ? (v[r] < pv ? v[r] : pv) : (v[r] > pv ? v[r] : pv);
                    }
                    __syncthreads();
                } else if (j >= 64) {
                    const int rx = (int)(j >> 6);   // 1 or 2
                    u64 nv[4];
                    #pragma unroll
                    for (int r = 0; r < 4; ++r) {
                        u64 pv = v[r ^ rx];
                        bool up = ((ii[r] & kk) == 0);
                        bool m = (((ii[r] & j) == 0) == up);
                        nv[r] = m ? (v[r] < pv ? v[r] : pv) : (v[r] > pv ? v[r] : pv);
                    }
                    #pragma unroll
                    for (int r = 0; r < 4; ++r) v[r] = nv[r];
                } else {
                    #pragma unroll
                    for (int r = 0; r < 4; ++r) {
                        u64 pv = shflx64(v[r], (int)j);
                        bool up = ((ii[r] & kk) == 0);
                        bool m = (((ii[r] & j) == 0) == up);
                        v[r] = m ? (v[r] < pv ? v[r] : pv) : (v[r] > pv ? v[r] : pv);
                    }
                }
            }
        }
        u64* cb = candbuf + (size_t)c * CAND_N + (size_t)s * KCAND;
        const bool rev = (s & 1);
        #pragma unroll
        for (int r = 0; r < 4; ++r) {
            if (ii[r] < KCAND) {
                int d = rev ? (KCAND - 1 - ii[r]) : ii[r];
                cb[d] = v[r];
            }
        }
    }
}

// ---- Stage 3: resume-bitonic(2048) + stride-17 mask + 2-wide scan ----
__global__ __launch_bounds__(1024)
void snms_kernel(const u64* __restrict__ candbuf,
                 const float4* __restrict__ boxes,
                 u32* __restrict__ keptbuf, u32* __restrict__ cnt2) {
    union SortMask {
        u64 sortbuf[2][CAND_N];       // 32 KB (sort phase)
        u32 bmask[KCAND * MSTR];      // 34.8 KB (mask/scan phase)
    };
    __shared__ SortMask sm;
    __shared__ float bxx[KCAND], byy[KCAND], bzz[KCAND], bww[KCAND];
    __shared__ float ar[KCAND], sc[KCAND];
    __shared__ u32 keepf[16], wbase[17];
    const int c = blockIdx.x, tid = threadIdx.x;
    const int l = tid & 63, w = tid >> 6;
    const int i0 = 128 * w + l, i1 = i0 + 64;

    // input: 4 sorted runs of 512, alternating asc/desc = post-stage-512 state
    const u64* cb = candbuf + (size_t)c * CAND_N;
    u64 v0 = cb[i0], v1 = cb[i1];
    int p = 0;
    #pragma unroll
    for (u32 kk = 1024; kk <= (u32)CAND_N; kk <<= 1) {
        #pragma unroll
        for (u32 j = kk >> 1; j > 0; j >>= 1) {
            if (j >= 128) {
                sm.sortbuf[p][i0] = v0; sm.sortbuf[p][i1] = v1;
                __syncthreads();
                u64 w0 = sm.sortbuf[p][i0 ^ j], w1 = sm.sortbuf[p][i1 ^ j];
                bool m0 = (((i0 & j) == 0) == ((i0 & kk) == 0));
                bool m1 = (((i1 & j) == 0) == ((i1 & kk) == 0));
                v0 = m0 ? (v0 < w0 ? v0 : w0) : (v0 > w0 ? v0 : w0);
                v1 = m1 ? (v1 < w1 ? v1 : w1) : (v1 > w1 ? v1 : w1);
                p ^= 1;
            } else if (j == 64) {
                bool up = ((i0 & kk) == 0);
                u64 mn = v0 < v1 ? v0 : v1, mx = v0 < v1 ? v1 : v0;
                v0 = up ? mn : mx; v1 = up ? mx : mn;
            } else {
                u64 w0 = shflx64(v0, (int)j), w1 = shflx64(v1, (int)j);
                bool m0 = (((i0 & j) == 0) == ((i0 & kk) == 0));
                bool m1 = (((i1 & j) == 0) == ((i1 & kk) == 0));
                v0 = m0 ? (v0 < w0 ? v0 : w0) : (v0 > w0 ? v0 : w0);
                v1 = m1 ? (v1 < w1 ? v1 : w1) : (v1 > w1 ? v1 : w1);
            }
        }
    }
    __syncthreads();   // sort done in registers; union switches to bmask

    // --- top-512 -> SoA ---
    if (w < 4) {   // i0,i1 < 512
        u32 idx0 = (u32)v0, key0 = ~((u32)(v0 >> 32));
        u32 idx1 = (u32)v1, key1 = ~((u32)(v1 >> 32));
        sc[i0] = unfkey(key0); sc[i1] = unfkey(key1);
        float4 b0 = boxes[idx0], b1 = boxes[idx1];
        bxx[i0] = b0.x; byy[i0] = b0.y; bzz[i0] = b0.z; bww[i0] = b0.w;
        bxx[i1] = b1.x; byy[i1] = b1.y; bzz[i1] = b1.z; bww[i1] = b1.w;
        ar[i0] = (b0.z - b0.x) * (b0.w - b0.y);
        ar[i1] = (b1.z - b1.x) * (b1.w - b1.y);
    }
    if (tid < 16) keepf[tid] = 0;
    __syncthreads();

    // --- upper-triangular IoU mask: 2 threads/row, 32-aligned split,
    //     direct disjoint word writes at stride-17 (conflict-free) ---
    {
        const int i = tid & (KCAND - 1);
        const int half = tid >> 9;
        const int count = (KCAND - 1) - i;
        int mid = (i + 1 + (count >> 1) + 31) & ~31;   // 32-aligned split
        if (mid > KCAND) mid = KCAND;
        const int j0 = half ? mid : (i + 1);
        const int j1 = half ? KCAND : mid;
        const int wsplit = mid >> 5;                   // word boundary
        const float bix = bxx[i], biy = byy[i], biz = bzz[i], biw = bww[i];
        const float ai = ar[i];
        u32 m[16];
        #pragma unroll
        for (int q = 0; q < 16; ++q) m[q] = 0;
        for (int j = j0; j < j1; ++j) {
            float xx1 = fmaxf(bix, bxx[j]), yy1 = fmaxf(biy, byy[j]);
            float xx2 = fminf(biz, bzz[j]), yy2 = fminf(biw, bww[j]);
            float inter = fmaxf(xx2 - xx1, 0.0f) * fmaxf(yy2 - yy1, 0.0f);
            float uni = ai + ar[j] - inter + 1e-8f;
            if (inter > 0.5f * uni) m[j >> 5] |= (1u << (j & 31));
        }
        const int qlo = half ? wsplit : 0;
        const int qhi = half ? 16 : wsplit;
        for (int q = qlo; q < qhi; ++q) sm.bmask[i * MSTR + q] = m[q];
    }
    __syncthreads();

    // --- greedy scan, wave 0: 2 candidates per readlane round ---
    if (tid < 64) {
        const int lw = tid & 15;
        u32 removed = 0, keepw = 0;
        u32 rA[8], rB[8]; float sA[8], sB[8];
        #pragma unroll
        for (int k = 0; k < 8; ++k) { rA[k] = sm.bmask[k * MSTR + lw]; sA[k] = sc[k]; }
        #pragma unroll 1
        for (int ch = 0; ch < 64; ch += 2) {
            const int tb1 = (ch + 1) * 8;
            #pragma unroll
            for (int k = 0; k < 8; ++k) { rB[k] = sm.bmask[(tb1 + k) * MSTR + lw]; sB[k] = sc[tb1 + k]; }
            {
                const int tb = ch * 8;
                #pragma unroll
                for (int k = 0; k < 8; k += 2) {
                    const int t = tb + k;
                    u32 rw   = (u32)__builtin_amdgcn_readlane((int)removed, t >> 5);
                    u32 mrow = (u32)__builtin_amdgcn_readlane((int)rA[k],   t >> 5);
                    bool d0 = (sA[k] > THRESH) && (((rw >> (t & 31)) & 1u) == 0u);
                    const u32 b1 = (u32)(t + 1) & 31u;
                    bool d1 = (sA[k + 1] > THRESH) && (((rw >> b1) & 1u) == 0u)
                              && !(d0 && ((mrow >> b1) & 1u));
                    removed |= (d0 ? rA[k] : 0u) | (d1 ? rA[k + 1] : 0u);
                    if (tid == (t >> 5))
                        keepw |= (d0 ? (1u << (t & 31)) : 0u) | (d1 ? (1u << b1) : 0u);
                }
            }
            const int tb2 = (ch + 2 < 64) ? (ch + 2) * 8 : 0;
            #pragma unroll
            for (int k = 0; k < 8; ++k) { rA[k] = sm.bmask[(tb2 + k) * MSTR + lw]; sA[k] = sc[tb2 + k]; }
            {
                #pragma unroll
                for (int k = 0; k < 8; k += 2) {
                    const int t = tb1 + k;
                    u32 rw   = (u32)__builtin_amdgcn_readlane((int)removed, t >> 5);
                    u32 mrow = (u32)__builtin_amdgcn_readlane((int)rB[k],   t >> 5);
                    bool d0 = (sB[k] > THRESH) && (((rw >> (t & 31)) & 1u) == 0u);
                    const u32 b1 = (u32)(t + 1) & 31u;
                    bool d1 = (sB[k + 1] > THRESH) && (((rw >> b1) & 1u) == 0u)
                              && !(d0 && ((mrow >> b1) & 1u));
                    removed |= (d0 ? rB[k] : 0u) | (d1 ? rB[k + 1] : 0u);
                    if (tid == (t >> 5))
                        keepw |= (d0 ? (1u << (t & 31)) : 0u) | (d1 ? (1u << b1) : 0u);
                }
            }
        }
        if (tid < 16) keepf[tid] = keepw;
    }
    __syncthreads();

    // --- compact kept (sorted order) to keptbuf, cap 100/class ---
    if (tid == 0) {
        u32 t = 0;
        for (int q = 0; q < 16; ++q) { wbase[q] = t; t += __popc(keepf[q]); }
        wbase[16] = t;
        cnt2[c] = (t < (u32)KEEP_CAP) ? t : (u32)KEEP_CAP;
    }
    __syncthreads();
    if (tid < KCAND) {
        u32 word = keepf[tid >> 5];
        u32 bit = (u32)tid & 31u;
        if ((word >> bit) & 1u) {
            u32 rank = wbase[tid >> 5] + __popc(word & ((1u << bit) - 1u));
            if (rank < (u32)KEEP_CAP) {
                float s = sc[tid];
                uint4 a, b;
                a.x = ~fkey(s);
                a.y = (u32)(c * KCAND + tid);
                a.z = __float_as_uint(bxx[tid]);
                a.w = __float_as_uint(byy[tid]);
                b.x = __float_as_uint(bzz[tid]);
                b.y = __float_as_uint(bww[tid]);
                b.z = __float_as_uint(s);
                b.w = 0u;
                uint4* e = (uint4*)(keptbuf + ((size_t)c * KEEP_CAP + rank) * 8);
                e[0] = a; e[1] = b;
            }
        }
    }
}

// ---- Stage 4: global top-100 via hist-select over <=9000 kept entries ----
__global__ __launch_bounds__(1024)
void final_kernel(const u32* __restrict__ keptbuf, const u32* __restrict__ cnt2,
                  float* __restrict__ out) {
    __shared__ u32 hist[NBINS];    // 32 KB
    __shared__ u32 csum[1024];     // 4 KB
    __shared__ u64 ebuf[FCAP];     // 4 KB keys
    __shared__ u32 eidx[FCAP];     // 2 KB payload (keptbuf entry index)
    __shared__ u32 scnt[C_N];
    __shared__ u32 sP;
    __shared__ int sN;
    const int tid = threadIdx.x;
    const int TOT = C_N * KEEP_CAP;   // 9000

    for (int i = tid; i < MAXDET * 7; i += 1024) out[i] = 0.0f;
    for (int i = tid; i < NBINS; i += 1024) hist[i] = 0;
    if (tid < C_N) scnt[tid] = cnt2[tid];
    if (tid == 0) { sN = 0; sP = NBINS - 1; }
    __syncthreads();

    for (int i = tid; i < TOT; i += 1024) {
        u32 c = (u32)i / KEEP_CAP, pp = (u32)i % KEEP_CAP;
        if (pp < scnt[c]) {
            u32 khi = keptbuf[(size_t)i * 8];   // a.x = ~fkey(s)
            atomicAdd(&hist[khi >> KSH], 1u);
        }
    }
    __syncthreads();
    u32 own = 0; const int lo = 8 * tid;
    #pragma unroll
    for (int j = 0; j < 8; ++j) own += hist[lo + j];
    csum[tid] = own;
    __syncthreads();
    for (int off = 1; off < 1024; off <<= 1) {
        u32 v = csum[tid];
        u32 a = (tid >= off) ? csum[tid - off] : 0u;
        __syncthreads();
        csum[tid] = v + a;
        __syncthreads();
    }
    const u32 incl = csum[tid], excl = incl - own;
    if (excl < (u32)MAXDET && incl >= (u32)MAXDET) {
        u32 cum = excl;
        for (int j = 0; j < 8; ++j) {
            u32 h = hist[lo + j];
            if (cum + h >= (u32)MAXDET) { sP = (u32)(lo + j); break; }
            cum += h;
        }
    }
    __syncthreads();
    const u32 P = sP;
    for (int i = tid; i < TOT; i += 1024) {
        u32 c = (u32)i / KEEP_CAP, pp = (u32)i % KEEP_CAP;
        if (pp < scnt[c]) {
            const uint2 v2 = *((const uint2*)(keptbuf + (size_t)i * 8));
            if ((v2.x >> KSH) <= P) {
                int p = atomicAdd(&sN, 1);
                if (p < FCAP) {
                    ebuf[p] = ((u64)v2.x << 32) | v2.y;
                    eidx[p] = (u32)i;
                }
            }
        }
    }
    __syncthreads();
    const int n = min(sN, FCAP);
    u32 m = 128; while ((int)m < n) m <<= 1;   // 128..512, uniform
    for (int i = tid; i < (int)m; i += 1024) if (i >= n) ebuf[i] = ~0ULL;
    __syncthreads();
    for (u32 kk = 2; kk <= m; kk <<= 1) {
        for (u32 j = kk >> 1; j > 0; j >>= 1) {
            u32 i = (u32)tid;
            if (i < m) {
                u32 ixj = i ^ j;
                if (ixj > i) {
                    u64 x = ebuf[i], y = ebuf[ixj];
                    bool up = ((i & kk) == 0);
                    if (up ? (x > y) : (x < y)) {
                        ebuf[i] = y; ebuf[ixj] = x;
                        u32 t = eidx[i]; eidx[i] = eidx[ixj]; eidx[ixj] = t;
                    }
                }
            }
            __syncthreads();
        }
    }
    if (tid < MAXDET && tid < n) {
        u64 comp = ebuf[tid];
        if (comp != ~0ULL) {
            const uint4* e = (const uint4*)(keptbuf + (size_t)eidx[tid] * 8);
            uint4 a = e[0], b = e[1];
            float* o = out + tid * 7;
            o[0] = 0.0f;
            o[1] = __uint_as_float(a.z); o[2] = __uint_as_float(a.w);
            o[3] = __uint_as_float(b.x); o[4] = __uint_as_float(b.y);
            o[5] = __uint_as_float(b.z);
            o[6] = (float)(((u32)comp) >> 9);   // low word = c*512+pos -> class
        }
    }
}

extern "C" void kernel_launch(void* const* d_in, const int* in_sizes, int n_in,
                              void* d_out, int out_size, void* d_ws, size_t ws_size,
                              hipStream_t stream) {
    const float* reg     = (const float*)d_in[1];
    const float* cls     = (const float*)d_in[2];
    const float* anchors = (const float*)d_in[3];
    float* out = (float*)d_out;

    char* ws = (char*)d_ws;
    size_t off = 0;
    auto alloc = [&](size_t bytes) -> void* {
        void* p = ws + off;
        off = (off + bytes + 255) & ~(size_t)255;
        return p;
    };
    u32*    keysT   = (u32*)   alloc((size_t)C_N * A_N * sizeof(u32));          // 39.8 MB
    float4* boxes   = (float4*)alloc((size_t)A_N * sizeof(float4));             // 1.77 MB
    u64*    candbuf = (u64*)   alloc((size_t)C_N * CAND_N * sizeof(u64));       // 1.47 MB
    u32*    keptbuf = (u32*)   alloc((size_t)C_N * KEEP_CAP * 8 * sizeof(u32)); // 288 KB
    u32*    cnt2    = (u32*)   alloc((size_t)C_N * sizeof(u32));
    (void)ws_size;

    prep_kernel<<<T_BLKS, 256, 0, stream>>>(cls, keysT);
    select_kernel<<<S_BLKS + D_BLKS, 256, 0, stream>>>(keysT, anchors, reg, boxes, candbuf);
    snms_kernel<<<C_N, 1024, 0, stream>>>(candbuf, boxes, keptbuf, cnt2);
    final_kernel<<<1, 1024, 0, stream>>>(keptbuf, cnt2, out);
}

// Round 14
// 217.283 us; speedup vs baseline: 1.0719x; 1.0719x over previous
//
#include <hip/hip_runtime.h>
#include <math.h>

// EfficientDet post-processing v14 == v11 (best measured: 216.6 us).
// prep(transpose vec4) -> select(sorted top-512 per (class,slice) + decode)
// -> snms(resume-bitonic + zero/atomicOr mask + readlane scan + compact)
// -> final(hist-select top-100 over <=9000 kept entries).

#define A_N   110484
#define C_N   90
#define KCAND 512
#define NBINS 8192        // 13-bit histogram bins (key >> 19)
#define KSH   19
#define MAXDET 100
#define IMG_F 768.0f
#define THRESH 0.05f
#define NS    4                                   // slices per class
#define VTOT  (A_N / 4)                           // 27621 vec4 units
#define VS4   ((VTOT + NS - 1) / NS)              // 6906
#define SL_CAP 1024                               // per-slice candidate cap
#define CAND_N (NS * KCAND)                       // 2048 per class (sorted runs)
#define KEEP_CAP 100
#define T_BLKS ((A_N + 63) / 64)                  // 1727 transpose blocks
#define S_BLKS (C_N * NS)                         // 360 select blocks
#define D_BLKS ((A_N + 255) / 256)                // 432 decode blocks
#define FCAP  512                                 // final collect capacity

typedef unsigned int u32;
typedef unsigned long long u64;

__device__ __forceinline__ u32 fkey(float f) {
    u32 u = __float_as_uint(f);
    return (u & 0x80000000u) ? ~u : (u | 0x80000000u);
}
__device__ __forceinline__ float unfkey(u32 k) {
    u32 u = (k & 0x80000000u) ? (k ^ 0x80000000u) : ~k;
    return __uint_as_float(u);
}
__device__ __forceinline__ u64 shflx64(u64 v, int m) {
    u32 lo = (u32)__shfl_xor((int)(u32)v, m, 64);
    u32 hi = (u32)__shfl_xor((int)(v >> 32), m, 64);
    return ((u64)hi << 32) | lo;
}

// ------- Stage 1: transpose (sigmoid->key, vec4 loads) -------
__global__ __launch_bounds__(256)
void prep_kernel(const float* __restrict__ cls,
                 u32* __restrict__ keysT) {
    __shared__ u32 tile[64 * 91];   // 23.3 KB, stride 91 (odd) = conflict-free
    const int a0 = blockIdx.x * 64;
    const int lim = min(64, A_N - a0);           // 64 or 20; lim*90 % 4 == 0
    const int n4 = (lim * C_N) >> 2;
    const float4* src4 = (const float4*)(cls + (size_t)a0 * C_N);
    for (int i4 = threadIdx.x; i4 < n4; i4 += 256) {
        float4 x4 = src4[i4];
        const u32 base = (u32)(4 * i4);
        float xs[4] = { x4.x, x4.y, x4.z, x4.w };
        #pragma unroll
        for (int k = 0; k < 4; ++k) {
            u32 i = base + k;
            u32 aa = i / C_N, c = i % C_N;
            float s = 1.0f / (1.0f + expf(-xs[k]));
            tile[aa * 91 + c] = fkey(s);
        }
    }
    __syncthreads();
    for (int j = threadIdx.x; j < C_N * 64; j += 256) {
        int c = j >> 6, aa = j & 63;
        if (aa < lim)
            keysT[(size_t)c * A_N + a0 + aa] = tile[aa * 91 + c];
    }
}

// ---- Stage 2: per-(class,slice) exact sorted top-512 (+ decode blocks) ----
__global__ __launch_bounds__(256)
void select_kernel(const u32* __restrict__ keysT,
                   const float* __restrict__ anchors,
                   const float* __restrict__ reg,
                   float4* __restrict__ boxes,
                   u64* __restrict__ candbuf) {
    __shared__ u32 hist[NBINS];    // 32 KB
    __shared__ u32 csum[256];
    __shared__ u64 lbuf[SL_CAP];   // 8 KB
    __shared__ u32 sPv;
    __shared__ int lcnt;
    const int tid = threadIdx.x;

    if (blockIdx.x >= S_BLKS) {    // decode blocks
        int a = (blockIdx.x - S_BLKS) * 256 + tid;
        if (a < A_N) {
            float4 an = ((const float4*)anchors)[a];
            float4 dl = ((const float4*)reg)[a];
            float wa = an.z - an.x, ha = an.w - an.y;
            float cx = an.x + 0.5f * wa + dl.x * wa;
            float cy = an.y + 0.5f * ha + dl.y * ha;
            float w = expf(dl.z) * wa;
            float h = expf(dl.w) * ha;
            float4 o;
            o.x = fminf(fmaxf(cx - 0.5f * w, 0.0f), IMG_F);
            o.y = fminf(fmaxf(cy - 0.5f * h, 0.0f), IMG_F);
            o.z = fminf(fmaxf(cx + 0.5f * w, 0.0f), IMG_F);
            o.w = fminf(fmaxf(cy + 0.5f * h, 0.0f), IMG_F);
            boxes[a] = o;
        }
        return;
    }
    const int c = blockIdx.x >> 2, s = blockIdx.x & 3;
    const int lo = s * VS4, hiEnd = min(VTOT, lo + VS4);
    const uint4* kv = (const uint4*)(keysT + (size_t)c * A_N);

    for (int i = tid; i < NBINS; i += 256) hist[i] = 0;
    if (tid == 0) { sPv = 0; lcnt = 0; }
    __syncthreads();
    for (int i = lo + tid; i < hiEnd; i += 256) {
        uint4 k = kv[i];
        atomicAdd(&hist[k.x >> KSH], 1u);
        atomicAdd(&hist[k.y >> KSH], 1u);
        atomicAdd(&hist[k.z >> KSH], 1u);
        atomicAdd(&hist[k.w >> KSH], 1u);
    }
    __syncthreads();
    u32 own = 0; const int hi = NBINS - 1 - 32 * tid;
    #pragma unroll 4
    for (int j = 0; j < 32; ++j) own += hist[hi - j];
    csum[tid] = own;
    __syncthreads();
    for (int off = 1; off < 256; off <<= 1) {
        u32 v = csum[tid];
        u32 a = (tid >= off) ? csum[tid - off] : 0u;
        __syncthreads();
        csum[tid] = v + a;
        __syncthreads();
    }
    const u32 incl = csum[tid], excl = incl - own;
    if (excl < (u32)KCAND && incl >= (u32)KCAND) {
        u32 cum = excl;
        for (int j = 0; j < 32; ++j) {
            u32 hv = hist[hi - j];
            if (cum + hv >= (u32)KCAND) { sPv = (u32)(hi - j); break; }
            cum += hv;
        }
    }
    __syncthreads();
    const u32 P = sPv;
    for (int i = lo + tid; i < hiEnd; i += 256) {
        uint4 k = kv[i];
        u32 base = (u32)(4 * i);
        if ((k.x >> KSH) >= P) {
            int p = atomicAdd(&lcnt, 1);
            if (p < SL_CAP) lbuf[p] = (((u64)(~k.x)) << 32) | base;
        }
        if ((k.y >> KSH) >= P) {
            int p = atomicAdd(&lcnt, 1);
            if (p < SL_CAP) lbuf[p] = (((u64)(~k.y)) << 32) | (base + 1);
        }
        if ((k.z >> KSH) >= P) {
            int p = atomicAdd(&lcnt, 1);
            if (p < SL_CAP) lbuf[p] = (((u64)(~k.z)) << 32) | (base + 2);
        }
        if ((k.w >> KSH) >= P) {
            int p = atomicAdd(&lcnt, 1);
            if (p < SL_CAP) lbuf[p] = (((u64)(~k.w)) << 32) | (base + 3);
        }
    }
    __syncthreads();
    const int n = min(lcnt, SL_CAP);   // n >= 512 guaranteed by pivot
    for (int i = tid; i < SL_CAP; i += 256) if (i >= n) lbuf[i] = ~0ULL;
    __syncthreads();

    // --- hybrid bitonic 1024 sort: 4 waves x (4 regs x 64 lanes) ---
    {
        const int l = tid & 63, w = tid >> 6;
        int ii[4]; u64 v[4];
        #pragma unroll
        for (int r = 0; r < 4; ++r) { ii[r] = 256 * w + 64 * r + l; v[r] = lbuf[ii[r]]; }
        __syncthreads();
        #pragma unroll
        for (u32 kk = 2; kk <= 1024; kk <<= 1) {
            #pragma unroll
            for (u32 j = kk >> 1; j > 0; j >>= 1) {
                if (j >= 256) {
                    #pragma unroll
                    for (int r = 0; r < 4; ++r) lbuf[ii[r]] = v[r];
                    __syncthreads();
                    #pragma unroll
                    for (int r = 0; r < 4; ++r) {
                        u64 pv = lbuf[ii[r] ^ j];
                        bool up = ((ii[r] & kk) == 0);
                        bool m = (((ii[r] & j) == 0) == up);
                        v[r] = m ? (v[r] < pv ? v[r] : pv) : (v[r] > pv ? v[r] : pv);
                    }
                    __syncthreads();
                } else if (j >= 64) {
                    const int rx = (int)(j >> 6);   // 1 or 2
                    u64 nv[4];
                    #pragma unroll
                    for (int r = 0; r < 4; ++r) {
                        u64 pv = v[r ^ rx];
                        bool up = ((ii[r] & kk) == 0);
                        bool m = (((ii[r] & j) == 0) == up);
                        nv[r] = m ? (v[r] < pv ? v[r] : pv) : (v[r] > pv ? v[r] : pv);
                    }
                    #pragma unroll
                    for (int r = 0; r < 4; ++r) v[r] = nv[r];
                } else {
                    #pragma unroll
                    for (int r = 0; r < 4; ++r) {
                        u64 pv = shflx64(v[r], (int)j);
                        bool up = ((ii[r] & kk) == 0);
                        bool m = (((ii[r] & j) == 0) == up);
                        v[r] = m ? (v[r] < pv ? v[r] : pv) : (v[r] > pv ? v[r] : pv);
                    }
                }
            }
        }
        u64* cb = candbuf + (size_t)c * CAND_N + (size_t)s * KCAND;
        const bool rev = (s & 1);
        #pragma unroll
        for (int r = 0; r < 4; ++r) {
            if (ii[r] < KCAND) {
                int d = rev ? (KCAND - 1 - ii[r]) : ii[r];
                cb[d] = v[r];
            }
        }
    }
}

// ---- Stage 3: resume-bitonic(2048) + mask + scan + compact ----
__global__ __launch_bounds__(1024)
void snms_kernel(const u64* __restrict__ candbuf,
                 const float4* __restrict__ boxes,
                 u32* __restrict__ keptbuf, u32* __restrict__ cnt2) {
    __shared__ u64 sortbuf[2][CAND_N];     // 32 KB; reused as bmask after sort
    __shared__ float bxx[KCAND], byy[KCAND], bzz[KCAND], bww[KCAND];
    __shared__ float ar[KCAND], sc[KCAND];
    __shared__ u32 keepf[16], wbase[17];
    u32* bmask = (u32*)&sortbuf[0][0];     // 512 rows x 16 words = 32 KB
    const int c = blockIdx.x, tid = threadIdx.x;
    const int l = tid & 63, w = tid >> 6;
    const int i0 = 128 * w + l, i1 = i0 + 64;

    // input: 4 sorted runs of 512, alternating asc/desc = post-stage-512 state
    const u64* cb = candbuf + (size_t)c * CAND_N;
    u64 v0 = cb[i0], v1 = cb[i1];
    int p = 0;
    #pragma unroll
    for (u32 kk = 1024; kk <= (u32)CAND_N; kk <<= 1) {
        #pragma unroll
        for (u32 j = kk >> 1; j > 0; j >>= 1) {
            if (j >= 128) {
                sortbuf[p][i0] = v0; sortbuf[p][i1] = v1;
                __syncthreads();
                u64 w0 = sortbuf[p][i0 ^ j], w1 = sortbuf[p][i1 ^ j];
                bool m0 = (((i0 & j) == 0) == ((i0 & kk) == 0));
                bool m1 = (((i1 & j) == 0) == ((i1 & kk) == 0));
                v0 = m0 ? (v0 < w0 ? v0 : w0) : (v0 > w0 ? v0 : w0);
                v1 = m1 ? (v1 < w1 ? v1 : w1) : (v1 > w1 ? v1 : w1);
                p ^= 1;
            } else if (j == 64) {
                bool up = ((i0 & kk) == 0);
                u64 mn = v0 < v1 ? v0 : v1, mx = v0 < v1 ? v1 : v0;
                v0 = up ? mn : mx; v1 = up ? mx : mn;
            } else {
                u64 w0 = shflx64(v0, (int)j), w1 = shflx64(v1, (int)j);
                bool m0 = (((i0 & j) == 0) == ((i0 & kk) == 0));
                bool m1 = (((i1 & j) == 0) == ((i1 & kk) == 0));
                v0 = m0 ? (v0 < w0 ? v0 : w0) : (v0 > w0 ? v0 : w0);
                v1 = m1 ? (v1 < w1 ? v1 : w1) : (v1 > w1 ? v1 : w1);
            }
        }
    }
    __syncthreads();   // sort done in registers; sortbuf free for bmask

    // --- top-512 -> SoA; zero mask ---
    if (w < 4) {   // i0,i1 < 512
        u32 idx0 = (u32)v0, key0 = ~((u32)(v0 >> 32));
        u32 idx1 = (u32)v1, key1 = ~((u32)(v1 >> 32));
        sc[i0] = unfkey(key0); sc[i1] = unfkey(key1);
        float4 b0 = boxes[idx0], b1 = boxes[idx1];
        bxx[i0] = b0.x; byy[i0] = b0.y; bzz[i0] = b0.z; bww[i0] = b0.w;
        bxx[i1] = b1.x; byy[i1] = b1.y; bzz[i1] = b1.z; bww[i1] = b1.w;
        ar[i0] = (b0.z - b0.x) * (b0.w - b0.y);
        ar[i1] = (b1.z - b1.x) * (b1.w - b1.y);
    }
    for (int i = tid; i < KCAND * 16; i += 1024) bmask[i] = 0;
    if (tid < 16) keepf[tid] = 0;
    __syncthreads();

    // --- upper-triangular IoU mask, 2 threads per row ---
    {
        const int i = tid & (KCAND - 1);
        const int half = tid >> 9;
        const int count = (KCAND - 1) - i;
        const int j0 = i + 1 + (half ? (count >> 1) : 0);
        const int j1 = half ? KCAND : (i + 1 + (count >> 1));
        const float bix = bxx[i], biy = byy[i], biz = bzz[i], biw = bww[i];
        const float ai = ar[i];
        u32 m[16];
        #pragma unroll
        for (int q = 0; q < 16; ++q) m[q] = 0;
        for (int j = j0; j < j1; ++j) {
            float xx1 = fmaxf(bix, bxx[j]), yy1 = fmaxf(biy, byy[j]);
            float xx2 = fminf(biz, bzz[j]), yy2 = fminf(biw, bww[j]);
            float inter = fmaxf(xx2 - xx1, 0.0f) * fmaxf(yy2 - yy1, 0.0f);
            float uni = ai + ar[j] - inter + 1e-8f;
            if (inter > 0.5f * uni) m[j >> 5] |= (1u << (j & 31));
        }
        #pragma unroll
        for (int q = 0; q < 16; ++q)
            if (m[q]) atomicOr(&bmask[i * 16 + q], m[q]);
    }
    __syncthreads();

    // --- greedy scan, wave 0; register-pipelined rows + readlane chain ---
    if (tid < 64) {
        const int lw = tid & 15;
        u32 removed = 0, keepw = 0;
        u32 rA[8], rB[8]; float sA[8], sB[8];
        #pragma unroll
        for (int k = 0; k < 8; ++k) { rA[k] = bmask[k * 16 + lw]; sA[k] = sc[k]; }
        #pragma unroll 1
        for (int ch = 0; ch < 64; ch += 2) {
            const int tb1 = (ch + 1) * 8;
            #pragma unroll
            for (int k = 0; k < 8; ++k) { rB[k] = bmask[(tb1 + k) * 16 + lw]; sB[k] = sc[tb1 + k]; }
            {
                const int tb = ch * 8;
                #pragma unroll
                for (int k = 0; k < 8; ++k) {
                    const int t = tb + k;
                    u32 rw = (u32)__builtin_amdgcn_readlane((int)removed, t >> 5);
                    bool d = (sA[k] > THRESH) && (((rw >> (t & 31)) & 1u) == 0u);
                    removed |= d ? rA[k] : 0u;
                    keepw |= (d && (tid == (t >> 5))) ? (1u << (t & 31)) : 0u;
                }
            }
            const int tb2 = (ch + 2 < 64) ? (ch + 2) * 8 : 0;
            #pragma unroll
            for (int k = 0; k < 8; ++k) { rA[k] = bmask[(tb2 + k) * 16 + lw]; sA[k] = sc[tb2 + k]; }
            {
                #pragma unroll
                for (int k = 0; k < 8; ++k) {
                    const int t = tb1 + k;
                    u32 rw = (u32)__builtin_amdgcn_readlane((int)removed, t >> 5);
                    bool d = (sB[k] > THRESH) && (((rw >> (t & 31)) & 1u) == 0u);
                    removed |= d ? rB[k] : 0u;
                    keepw |= (d && (tid == (t >> 5))) ? (1u << (t & 31)) : 0u;
                }
            }
        }
        if (tid < 16) keepf[tid] = keepw;
    }
    __syncthreads();

    // --- compact kept (sorted order) to keptbuf, cap 100/class ---
    if (tid == 0) {
        u32 t = 0;
        for (int q = 0; q < 16; ++q) { wbase[q] = t; t += __popc(keepf[q]); }
        wbase[16] = t;
        cnt2[c] = (t < (u32)KEEP_CAP) ? t : (u32)KEEP_CAP;
    }
    __syncthreads();
    if (tid < KCAND) {
        u32 word = keepf[tid >> 5];
        u32 bit = (u32)tid & 31u;
        if ((word >> bit) & 1u) {
            u32 rank = wbase[tid >> 5] + __popc(word & ((1u << bit) - 1u));
            if (rank < (u32)KEEP_CAP) {
                float s = sc[tid];
                uint4 a, b;
                a.x = ~fkey(s);
                a.y = (u32)(c * KCAND + tid);
                a.z = __float_as_uint(bxx[tid]);
                a.w = __float_as_uint(byy[tid]);
                b.x = __float_as_uint(bzz[tid]);
                b.y = __float_as_uint(bww[tid]);
                b.z = __float_as_uint(s);
                b.w = 0u;
                uint4* e = (uint4*)(keptbuf + ((size_t)c * KEEP_CAP + rank) * 8);
                e[0] = a; e[1] = b;
            }
        }
    }
}

// ---- Stage 4: global top-100 via hist-select over <=9000 kept entries ----
__global__ __launch_bounds__(1024)
void final_kernel(const u32* __restrict__ keptbuf, const u32* __restrict__ cnt2,
                  float* __restrict__ out) {
    __shared__ u32 hist[NBINS];    // 32 KB
    __shared__ u32 csum[1024];     // 4 KB
    __shared__ u64 ebuf[FCAP];     // 4 KB keys
    __shared__ u32 eidx[FCAP];     // 2 KB payload (keptbuf entry index)
    __shared__ u32 scnt[C_N];
    __shared__ u32 sP;
    __shared__ int sN;
    const int tid = threadIdx.x;
    const int TOT = C_N * KEEP_CAP;   // 9000

    for (int i = tid; i < MAXDET * 7; i += 1024) out[i] = 0.0f;
    for (int i = tid; i < NBINS; i += 1024) hist[i] = 0;
    if (tid < C_N) scnt[tid] = cnt2[tid];
    if (tid == 0) { sN = 0; sP = NBINS - 1; }
    __syncthreads();

    // hist over composite high word (smaller = better -> ascending pivot)
    for (int i = tid; i < TOT; i += 1024) {
        u32 c = (u32)i / KEEP_CAP, pp = (u32)i % KEEP_CAP;
        if (pp < scnt[c]) {
            u32 khi = keptbuf[(size_t)i * 8];   // a.x = ~fkey(s)
            atomicAdd(&hist[khi >> KSH], 1u);
        }
    }
    __syncthreads();
    u32 own = 0; const int lo = 8 * tid;
    #pragma unroll
    for (int j = 0; j < 8; ++j) own += hist[lo + j];
    csum[tid] = own;
    __syncthreads();
    for (int off = 1; off < 1024; off <<= 1) {
        u32 v = csum[tid];
        u32 a = (tid >= off) ? csum[tid - off] : 0u;
        __syncthreads();
        csum[tid] = v + a;
        __syncthreads();
    }
    const u32 incl = csum[tid], excl = incl - own;
    if (excl < (u32)MAXDET && incl >= (u32)MAXDET) {
        u32 cum = excl;
        for (int j = 0; j < 8; ++j) {
            u32 h = hist[lo + j];
            if (cum + h >= (u32)MAXDET) { sP = (u32)(lo + j); break; }
            cum += h;
        }
    }
    __syncthreads();
    const u32 P = sP;
    for (int i = tid; i < TOT; i += 1024) {
        u32 c = (u32)i / KEEP_CAP, pp = (u32)i % KEEP_CAP;
        if (pp < scnt[c]) {
            const uint2 v2 = *((const uint2*)(keptbuf + (size_t)i * 8));
            if ((v2.x >> KSH) <= P) {
                int p = atomicAdd(&sN, 1);
                if (p < FCAP) {
                    ebuf[p] = ((u64)v2.x << 32) | v2.y;
                    eidx[p] = (u32)i;
                }
            }
        }
    }
    __syncthreads();
    const int n = min(sN, FCAP);
    u32 m = 128; while ((int)m < n) m <<= 1;   // 128..512, uniform
    for (int i = tid; i < (int)m; i += 1024) if (i >= n) ebuf[i] = ~0ULL;
    __syncthreads();
    for (u32 kk = 2; kk <= m; kk <<= 1) {
        for (u32 j = kk >> 1; j > 0; j >>= 1) {
            u32 i = (u32)tid;
            if (i < m) {
                u32 ixj = i ^ j;
                if (ixj > i) {
                    u64 x = ebuf[i], y = ebuf[ixj];
                    bool up = ((i & kk) == 0);
                    if (up ? (x > y) : (x < y)) {
                        ebuf[i] = y; ebuf[ixj] = x;
                        u32 t = eidx[i]; eidx[i] = eidx[ixj]; eidx[ixj] = t;
                    }
                }
            }
            __syncthreads();
        }
    }
    if (tid < MAXDET && tid < n) {
        u64 comp = ebuf[tid];
        if (comp != ~0ULL) {
            const uint4* e = (const uint4*)(keptbuf + (size_t)eidx[tid] * 8);
            uint4 a = e[0], b = e[1];
            float* o = out + tid * 7;
            o[0] = 0.0f;
            o[1] = __uint_as_float(a.z); o[2] = __uint_as_float(a.w);
            o[3] = __uint_as_float(b.x); o[4] = __uint_as_float(b.y);
            o[5] = __uint_as_float(b.z);
            o[6] = (float)(((u32)comp) >> 9);   // low word = c*512+pos -> class
        }
    }
}

extern "C" void kernel_launch(void* const* d_in, const int* in_sizes, int n_in,
                              void* d_out, int out_size, void* d_ws, size_t ws_size,
                              hipStream_t stream) {
    const float* reg     = (const float*)d_in[1];
    const float* cls     = (const float*)d_in[2];
    const float* anchors = (const float*)d_in[3];
    float* out = (float*)d_out;

    char* ws = (char*)d_ws;
    size_t off = 0;
    auto alloc = [&](size_t bytes) -> void* {
        void* p = ws + off;
        off = (off + bytes + 255) & ~(size_t)255;
        return p;
    };
    u32*    keysT   = (u32*)   alloc((size_t)C_N * A_N * sizeof(u32));          // 39.8 MB
    float4* boxes   = (float4*)alloc((size_t)A_N * sizeof(float4));             // 1.77 MB
    u64*    candbuf = (u64*)   alloc((size_t)C_N * CAND_N * sizeof(u64));       // 1.47 MB
    u32*    keptbuf = (u32*)   alloc((size_t)C_N * KEEP_CAP * 8 * sizeof(u32)); // 288 KB
    u32*    cnt2    = (u32*)   alloc((size_t)C_N * sizeof(u32));
    (void)ws_size;

    prep_kernel<<<T_BLKS, 256, 0, stream>>>(cls, keysT);
    select_kernel<<<S_BLKS + D_BLKS, 256, 0, stream>>>(keysT, anchors, reg, boxes, candbuf);
    snms_kernel<<<C_N, 1024, 0, stream>>>(candbuf, boxes, keptbuf, cnt2);
    final_kernel<<<1, 1024, 0, stream>>>(keptbuf, cnt2, out);
}